// Round 12
// baseline (436.095 us; speedup 1.0000x reference)
//
#include <hip/hip_runtime.h>
#include <hip/hip_bf16.h>

#define NN 8192
#define KK 32

typedef __attribute__((ext_vector_type(8))) short short8v;   // 8 bf16 in 4 VGPRs
typedef __attribute__((ext_vector_type(4))) float float4v;   // MFMA 16x16 acc

__device__ __forceinline__ float wave_reduce_sum(float v) {
    #pragma unroll
    for (int off = 32; off > 0; off >>= 1) v += __shfl_down(v, off);
    return v;
}
__device__ __forceinline__ unsigned short f2bf(float x) {  // RNE fp32->bf16
    unsigned int u = __float_as_uint(x);
    return (unsigned short)((u + 0x7fffu + ((u >> 16) & 1u)) >> 16);
}

// ---------- K0: pack A (fp32 {0,1}) into bitmask, 1 bit/elem = 8 MB total.
// One wave per row; contiguous 1KB float4 reads (fill-like streaming pattern).
// Layout: Abits[(row*32 + seg)*4 + w], bit l <-> col = seg*256 + 4*l + w. ----------
__global__ __launch_bounds__(256) void k_pack(const float* __restrict__ A,
                                              unsigned long long* __restrict__ Abits) {
    const int lane = threadIdx.x & 63;
    const int row  = blockIdx.x * 4 + (threadIdx.x >> 6);
    const float* ar = &A[(size_t)row * NN];
    #pragma unroll 2
    for (int it = 0; it < 32; ++it) {
        const float4 a = *(const float4*)&ar[it * 256 + lane * 4];
        const unsigned long long b0 = __ballot(a.x != 0.f);
        const unsigned long long b1 = __ballot(a.y != 0.f);
        const unsigned long long b2 = __ballot(a.z != 0.f);
        const unsigned long long b3 = __ballot(a.w != 0.f);
        if (lane < 4) {
            const unsigned long long v =
                (lane == 0) ? b0 : (lane == 1) ? b1 : (lane == 2) ? b2 : b3;
            Abits[((size_t)row * 32 + it) * 4 + lane] = v;
        }
    }
}

// ---------- K1: fused E' = (exp X / colsum) @ exp(C), plus sC[l] = sum_n exp(C[n][l])
__global__ __launch_bounds__(256) void kE(const float* __restrict__ X,
                                          const float* __restrict__ C,
                                          float* __restrict__ Ep,
                                          float* __restrict__ sC) {
    __shared__ float xe[KK * 33];   // exp(X[k][n]) [k][n]
    __shared__ float ce[32 * 33];   // exp(C[n][l]) [n][l]
    __shared__ float xs[32];        // 1 / colsum_k exp(X[k][n])
    const int tid = threadIdx.x;
    const int r = tid >> 5, q = tid & 31;
    const int nb = blockIdx.x * 32;
    #pragma unroll
    for (int u = 0; u < 4; ++u) {
        xe[(r + 8 * u) * 33 + q] = __expf(X[(size_t)(r + 8 * u) * NN + nb + q]);
        ce[(r + 8 * u) * 33 + q] = __expf(C[(size_t)(nb + r + 8 * u) * KK + q]);
    }
    __syncthreads();
    if (tid < 32) {
        float s = 0.f;
        #pragma unroll
        for (int k = 0; k < 32; ++k) s += xe[k * 33 + tid];
        xs[tid] = 1.f / s;
    } else if (tid < 64) {
        const int l = tid - 32;
        float s = 0.f;
        #pragma unroll
        for (int n = 0; n < 32; ++n) s += ce[n * 33 + l];
        atomicAdd(&sC[l], s);
    }
    __syncthreads();
    #pragma unroll
    for (int u = 0; u < 4; ++u) {
        const int k = r + 8 * u;
        float acc = 0.f;
        #pragma unroll
        for (int n = 0; n < 32; ++n)
            acc = fmaf(xe[k * 33 + n] * xs[n], ce[n * 33 + q], acc);
        atomicAdd(&Ep[k * KK + q], acc);
    }
}

// ---------- K2: prep. M = D^-1 E'^T E' D^-1 locally; f, Xh, Wh bf16; diag sp ----------
__global__ __launch_bounds__(256) void kp_prep(
    const float* __restrict__ X, const float* __restrict__ beta,
    const float* __restrict__ a_ptr, const float* __restrict__ Ep,
    const float* __restrict__ sC,
    float* __restrict__ f, unsigned short* __restrict__ Xh,
    unsigned short* __restrict__ Wh, double* __restrict__ acc) {
    __shared__ float el[KK * 33];   // E'[k][l]
    __shared__ float rs[32];
    __shared__ float Ml[KK * KK];
    const int tid = threadIdx.x;  // 256
    const int r = tid >> 5, q = tid & 31;
    #pragma unroll
    for (int u = 0; u < 4; ++u)
        el[(r + 8 * u) * 33 + q] = Ep[(r + 8 * u) * KK + q];
    if (tid < 32) rs[tid] = 1.f / sC[tid];
    __syncthreads();
    #pragma unroll
    for (int u = 0; u < 4; ++u) {
        const int l1 = r + 8 * u;
        float m = 0.f;
        #pragma unroll
        for (int k = 0; k < KK; ++k)
            m = fmaf(el[k * 33 + l1], el[k * 33 + q], m);
        Ml[l1 * KK + q] = m * rs[l1] * rs[q];
    }
    __syncthreads();

    const int n = blockIdx.x * 256 + tid;
    float x[KK], v[KK];
    #pragma unroll
    for (int k = 0; k < KK; ++k) x[k] = X[(size_t)k * NN + n];
    const float a = a_ptr[0];
    const float two_a = 2.f * a;
    #pragma unroll
    for (int l = 0; l < KK; ++l) {
        float s = 0.f;
        #pragma unroll
        for (int k = 0; k < KK; ++k) s = fmaf(Ml[l * KK + k], x[k], s);
        v[l] = two_a * s;                     // w = 2a M x
    }
    float q2 = 0.f;
    #pragma unroll
    for (int l = 0; l < KK; ++l) q2 = fmaf(x[l], v[l], q2);
    const float b = beta[n];
    const float fn = b - 0.5f * q2;           // f = beta - a x^T M x
    f[n] = fn;

    union PK { unsigned short u[8]; short8v s; };
    PK xh, wh;
    #pragma unroll
    for (int g = 0; g < 4; ++g) {
        #pragma unroll
        for (int e = 0; e < 8; ++e) {
            const int k = g * 8 + e;
            xh.u[e] = f2bf(x[k]);
            wh.u[e] = f2bf(v[k]);
        }
        *(short8v*)&Xh[(size_t)n * KK + g * 8] = xh.s;
        *(short8v*)&Wh[(size_t)n * KK + g * 8] = wh.s;
    }
    // diagonal softplus: theta_ii = 2*beta_i exactly (z_ii = 0)
    const float th = 2.f * b;
    float sp = fmaxf(th, 0.f) + __logf(1.f + __expf(-fabsf(th)));
    sp = wave_reduce_sum(sp);
    if ((tid & 63) == 0) atomicAdd(&acc[2], (double)sp);
}

// ---------- K3: pair kernel on BIT-PACKED A. Wave = 32 i x 256 j, swapped MFMA
// (d = mfma(W,X): d[r] = S[i = ibase+l15(+16)][j = jb + 4*g4 + r]).
// A bits for the wave's whole footprint: 2 rows x 4 u64 = 64 B, loaded once. ----------
__global__ __launch_bounds__(256, 6) void k_pair(
    const unsigned long long* __restrict__ Abits, const float* __restrict__ f,
    const unsigned short* __restrict__ Xh, const unsigned short* __restrict__ Wh,
    float* __restrict__ part) {
    const int tid  = threadIdx.x;
    const int lane = tid & 63;
    const int l15  = lane & 15;
    const int g4   = lane >> 4;
    const int klo  = g4 << 3;
    const int r0   = g4 << 2;
    const int wid  = blockIdx.x * 4 + (tid >> 6);
    const int ibase = (wid >> 5) << 5;   // 256 i-tiles of 32 rows
    const int jc    = (wid & 31) << 8;   // 32 j-chunks of 256
    const int seg   = jc >> 8;

    const short8v xh0 = *(const short8v*)&Xh[(size_t)(ibase + l15) * KK + klo];
    const short8v xh1 = *(const short8v*)&Xh[(size_t)(ibase + 16 + l15) * KK + klo];
    const float fi0 = f[ibase + l15];
    const float fi1 = f[ibase + 16 + l15];

    const ulonglong2* p0 =
        (const ulonglong2*)&Abits[((size_t)(ibase + l15) * 32 + seg) * 4];
    const ulonglong2* p1 =
        (const ulonglong2*)&Abits[((size_t)(ibase + 16 + l15) * 32 + seg) * 4];
    const ulonglong2 q00 = p0[0], q01 = p0[1];
    const ulonglong2 q10 = p1[0], q11 = p1[1];
    const unsigned lo0[4] = {(unsigned)q00.x, (unsigned)q00.y,
                             (unsigned)q01.x, (unsigned)q01.y};
    const unsigned hi0[4] = {(unsigned)(q00.x >> 32), (unsigned)(q00.y >> 32),
                             (unsigned)(q01.x >> 32), (unsigned)(q01.y >> 32)};
    const unsigned lo1[4] = {(unsigned)q10.x, (unsigned)q10.y,
                             (unsigned)q11.x, (unsigned)q11.y};
    const unsigned hi1[4] = {(unsigned)(q10.x >> 32), (unsigned)(q10.y >> 32),
                             (unsigned)(q11.x >> 32), (unsigned)(q11.y >> 32)};

    float accA = 0.f, accS = 0.f;
    for (int half = 0; half < 2; ++half) {
        unsigned c0[4], c1[4];
        #pragma unroll
        for (int r = 0; r < 4; ++r) {
            c0[r] = half ? hi0[r] : lo0[r];
            c1[r] = half ? hi1[r] : lo1[r];
        }
        #pragma unroll 2
        for (int jt2 = 0; jt2 < 8; ++jt2) {
            const int jb = jc + (((half << 3) + jt2) << 4);
            const unsigned sh = (unsigned)(jt2 << 2) + (unsigned)g4;
            const short8v wf = *(const short8v*)&Wh[(size_t)(jb + l15) * KK + klo];
            const float4 fj = *(const float4*)&f[jb + r0];
            float4v d0 = {0.f, 0.f, 0.f, 0.f};
            float4v d1 = {0.f, 0.f, 0.f, 0.f};
            d0 = __builtin_amdgcn_mfma_f32_16x16x32_bf16(wf, xh0, d0, 0, 0, 0);
            d1 = __builtin_amdgcn_mfma_f32_16x16x32_bf16(wf, xh1, d1, 0, 0, 0);
            const float* fjp = (const float*)&fj;
            #pragma unroll
            for (int r = 0; r < 4; ++r) {
                const float av0 = (float)((c0[r] >> sh) & 1u);
                const float av1 = (float)((c1[r] >> sh) & 1u);
                const float th0 = fi0 + fjp[r] + d0[r];
                const float th1 = fi1 + fjp[r] + d1[r];
                accA = fmaf(th0, av0, accA);
                accA = fmaf(th1, av1, accA);
                accS += fmaxf(th0, 0.f) + __logf(1.f + __expf(-fabsf(th0)));
                accS += fmaxf(th1, 0.f) + __logf(1.f + __expf(-fabsf(th1)));
            }
        }
    }

    accA = wave_reduce_sum(accA);
    accS = wave_reduce_sum(accS);
    __shared__ float rA[4], rS[4];
    if (lane == 0) { rA[tid >> 6] = accA; rS[tid >> 6] = accS; }
    __syncthreads();
    if (tid == 0) {
        part[blockIdx.x * 2]     = rA[0] + rA[1] + rA[2] + rA[3];
        part[blockIdx.x * 2 + 1] = rS[0] + rS[1] + rS[2] + rS[3];
    }
}

// ---------- K4: final deterministic reduction of 2048 block partials ----------
__global__ __launch_bounds__(1024) void kz_final(const float* __restrict__ part,
                                                 const double* __restrict__ acc,
                                                 float* __restrict__ out) {
    const int t = threadIdx.x;  // 1024 threads
    double dA = (double)part[2 * t]     + (double)part[2 * (t + 1024)];
    double dS = (double)part[2 * t + 1] + (double)part[2 * (t + 1024) + 1];
    #pragma unroll
    for (int off = 32; off > 0; off >>= 1) {
        dA += __shfl_down(dA, off);
        dS += __shfl_down(dS, off);
    }
    __shared__ double sA[16], sS[16];
    if ((t & 63) == 0) { sA[t >> 6] = dA; sS[t >> 6] = dS; }
    __syncthreads();
    if (t == 0) {
        double a = 0.0, s = 0.0;
        #pragma unroll
        for (int u = 0; u < 16; ++u) { a += sA[u]; s += sS[u]; }
        out[0] = (float)(0.5 * (a - (s - acc[2])));
    }
}

extern "C" void kernel_launch(void* const* d_in, const int* in_sizes, int n_in,
                              void* d_out, int out_size, void* d_ws, size_t ws_size,
                              hipStream_t stream) {
    const float* Ain    = (const float*)d_in[0];  // (N, N)
    const float* betain = (const float*)d_in[1];  // (N,)
    const float* ain    = (const float*)d_in[2];  // (1,)
    const float* Xin    = (const float*)d_in[3];  // (K, N)
    const float* Cin    = (const float*)d_in[4];  // (N, K)
    float* out = (float*)d_out;

    char* ws = (char*)d_ws;
    float*              Ep    = (float*)(ws + 0);                 // 4 KB
    double*             acc   = (double*)(ws + 4096);             // 3 doubles
    float*              sC    = (float*)(ws + 4224);              // 128 B
    float*              f     = (float*)(ws + 8704);              // 32 KB
    float*              part  = (float*)(ws + 49152);             // 16 KB
    unsigned short*     Xh    = (unsigned short*)(ws + 65536);    // 512 KB
    unsigned short*     Wh    = (unsigned short*)(ws + 589824);   // 512 KB
    unsigned long long* Abits = (unsigned long long*)(ws + 1114112);  // 8 MB
    // total ~9.1 MB

    hipMemsetAsync(ws, 0, 4352, stream);  // zero Ep + accs + sC

    k_pack<<<2048, 256, 0, stream>>>(Ain, Abits);
    kE<<<256, 256, 0, stream>>>(Xin, Cin, Ep, sC);
    kp_prep<<<NN / 256, 256, 0, stream>>>(Xin, betain, ain, Ep, sC, f, Xh, Wh, acc);
    k_pair<<<2048, 256, 0, stream>>>(Abits, f, Xh, Wh, part);
    kz_final<<<1, 1024, 0, stream>>>(part, acc, out);
}

// Round 14
// 404.495 us; speedup vs baseline: 1.0781x; 1.0781x over previous
//
#include <hip/hip_runtime.h>
#include <hip/hip_bf16.h>

#define NN 8192
#define KK 32

typedef __attribute__((ext_vector_type(8))) short short8v;   // 8 bf16 in 4 VGPRs
typedef __attribute__((ext_vector_type(4))) float float4v;   // MFMA 16x16 acc

__device__ __forceinline__ float wave_reduce_sum(float v) {
    #pragma unroll
    for (int off = 32; off > 0; off >>= 1) v += __shfl_down(v, off);
    return v;
}
__device__ __forceinline__ unsigned short f2bf(float x) {  // RNE fp32->bf16
    unsigned int u = __float_as_uint(x);
    return (unsigned short)((u + 0x7fffu + ((u >> 16) & 1u)) >> 16);
}

// ---------- K1: fused E' = (exp X / colsum) @ exp(C), plus sC[l] = sum_n exp(C[n][l])
__global__ __launch_bounds__(256) void kE(const float* __restrict__ X,
                                          const float* __restrict__ C,
                                          float* __restrict__ Ep,
                                          float* __restrict__ sC) {
    __shared__ float xe[KK * 33];   // exp(X[k][n]) [k][n]
    __shared__ float ce[32 * 33];   // exp(C[n][l]) [n][l]
    __shared__ float xs[32];        // 1 / colsum_k exp(X[k][n])
    const int tid = threadIdx.x;
    const int r = tid >> 5, q = tid & 31;
    const int nb = blockIdx.x * 32;
    #pragma unroll
    for (int u = 0; u < 4; ++u) {
        xe[(r + 8 * u) * 33 + q] = __expf(X[(size_t)(r + 8 * u) * NN + nb + q]);
        ce[(r + 8 * u) * 33 + q] = __expf(C[(size_t)(nb + r + 8 * u) * KK + q]);
    }
    __syncthreads();
    if (tid < 32) {
        float s = 0.f;
        #pragma unroll
        for (int k = 0; k < 32; ++k) s += xe[k * 33 + tid];
        xs[tid] = 1.f / s;
    } else if (tid < 64) {
        const int l = tid - 32;
        float s = 0.f;
        #pragma unroll
        for (int n = 0; n < 32; ++n) s += ce[n * 33 + l];
        atomicAdd(&sC[l], s);
    }
    __syncthreads();
    #pragma unroll
    for (int u = 0; u < 4; ++u) {
        const int k = r + 8 * u;
        float acc = 0.f;
        #pragma unroll
        for (int n = 0; n < 32; ++n)
            acc = fmaf(xe[k * 33 + n] * xs[n], ce[n * 33 + q], acc);
        atomicAdd(&Ep[k * KK + q], acc);
    }
}

// ---------- K2: prep. M = D^-1 E'^T E' D^-1 locally; f, Xh, Wh bf16; diag sp ----------
__global__ __launch_bounds__(256) void kp_prep(
    const float* __restrict__ X, const float* __restrict__ beta,
    const float* __restrict__ a_ptr, const float* __restrict__ Ep,
    const float* __restrict__ sC,
    float* __restrict__ f, unsigned short* __restrict__ Xh,
    unsigned short* __restrict__ Wh, double* __restrict__ acc) {
    __shared__ float el[KK * 33];   // E'[k][l]
    __shared__ float rs[32];
    __shared__ float Ml[KK * KK];
    const int tid = threadIdx.x;  // 256
    const int r = tid >> 5, q = tid & 31;
    #pragma unroll
    for (int u = 0; u < 4; ++u)
        el[(r + 8 * u) * 33 + q] = Ep[(r + 8 * u) * KK + q];
    if (tid < 32) rs[tid] = 1.f / sC[tid];
    __syncthreads();
    #pragma unroll
    for (int u = 0; u < 4; ++u) {
        const int l1 = r + 8 * u;
        float m = 0.f;
        #pragma unroll
        for (int k = 0; k < KK; ++k)
            m = fmaf(el[k * 33 + l1], el[k * 33 + q], m);
        Ml[l1 * KK + q] = m * rs[l1] * rs[q];
    }
    __syncthreads();

    const int n = blockIdx.x * 256 + tid;
    float x[KK], v[KK];
    #pragma unroll
    for (int k = 0; k < KK; ++k) x[k] = X[(size_t)k * NN + n];
    const float a = a_ptr[0];
    const float two_a = 2.f * a;
    #pragma unroll
    for (int l = 0; l < KK; ++l) {
        float s = 0.f;
        #pragma unroll
        for (int k = 0; k < KK; ++k) s = fmaf(Ml[l * KK + k], x[k], s);
        v[l] = two_a * s;                     // w = 2a M x
    }
    float q2 = 0.f;
    #pragma unroll
    for (int l = 0; l < KK; ++l) q2 = fmaf(x[l], v[l], q2);
    const float b = beta[n];
    const float fn = b - 0.5f * q2;           // f = beta - a x^T M x
    f[n] = fn;

    union PK { unsigned short u[8]; short8v s; };
    PK xh, wh;
    #pragma unroll
    for (int g = 0; g < 4; ++g) {
        #pragma unroll
        for (int e = 0; e < 8; ++e) {
            const int k = g * 8 + e;
            xh.u[e] = f2bf(x[k]);
            wh.u[e] = f2bf(v[k]);
        }
        *(short8v*)&Xh[(size_t)n * KK + g * 8] = xh.s;
        *(short8v*)&Wh[(size_t)n * KK + g * 8] = wh.s;
    }
    // diagonal softplus: theta_ii = 2*beta_i exactly (z_ii = 0)
    const float th = 2.f * b;
    float sp = fmaxf(th, 0.f) + __logf(1.f + __expf(-fabsf(th)));
    sp = wave_reduce_sum(sp);
    if ((tid & 63) == 0) atomicAdd(&acc[2], (double)sp);
}

// ---------- K3: unified pair kernel, wave = 32 i x 256 j.
// SWAPPED MFMA: d = mfma(W_frag, X_frag) -> D[col=i (lane&15), row=j (g4*4+r)],
// so A is loaded as ROW-CONTIGUOUS float4 per lane (16B/lane, 1 load per 16x16 tile
// per s, vs 4 scalar loads in D-layout). ----------
__global__ __launch_bounds__(256, 6) void k_pair(
    const float* __restrict__ A, const float* __restrict__ f,
    const unsigned short* __restrict__ Xh, const unsigned short* __restrict__ Wh,
    float* __restrict__ part) {
    const int tid  = threadIdx.x;
    const int lane = tid & 63;
    const int l15  = lane & 15;
    const int klo  = (lane >> 4) << 3;
    const int r0   = (lane >> 4) << 2;
    const int wid  = blockIdx.x * 4 + (tid >> 6);
    const int ibase = (wid >> 5) << 5;   // 256 i-tiles of 32 rows
    const int jc    = (wid & 31) << 8;   // 32 j-chunks of 256

    const short8v xh0 = *(const short8v*)&Xh[(size_t)(ibase + l15) * KK + klo];
    const short8v xh1 = *(const short8v*)&Xh[(size_t)(ibase + 16 + l15) * KK + klo];
    const float fi0 = f[ibase + l15];        // f_i for s=0 (i = ibase + l15)
    const float fi1 = f[ibase + 16 + l15];   // f_i for s=1

    const float* arow0 = &A[(size_t)(ibase + l15) * NN + jc + r0];
    const float* arow1 = &A[(size_t)(ibase + 16 + l15) * NN + jc + r0];

    float accA = 0.f, accS = 0.f;
    #pragma unroll 2
    for (int jt = 0; jt < 16; ++jt) {
        const int jb = jc + (jt << 4);
        const short8v wf = *(const short8v*)&Wh[(size_t)(jb + l15) * KK + klo];
        const float4 fj = *(const float4*)&f[jb + r0];        // f_j, j = jb+r0+r
        const float4 a0 = *(const float4*)(arow0 + (jt << 4)); // A[i0][jb+r0 ..+3]
        const float4 a1 = *(const float4*)(arow1 + (jt << 4)); // A[i1][jb+r0 ..+3]
        float4v d0 = {0.f, 0.f, 0.f, 0.f};
        float4v d1 = {0.f, 0.f, 0.f, 0.f};
        d0 = __builtin_amdgcn_mfma_f32_16x16x32_bf16(wf, xh0, d0, 0, 0, 0);
        d1 = __builtin_amdgcn_mfma_f32_16x16x32_bf16(wf, xh1, d1, 0, 0, 0);

        {
            float th, sp;
            th = fi0 + fj.x + d0[0];
            accA = fmaf(th, a0.x, accA);
            sp = fmaxf(th, 0.f) + __logf(1.f + __expf(-fabsf(th))); accS += sp;
            th = fi0 + fj.y + d0[1];
            accA = fmaf(th, a0.y, accA);
            sp = fmaxf(th, 0.f) + __logf(1.f + __expf(-fabsf(th))); accS += sp;
            th = fi0 + fj.z + d0[2];
            accA = fmaf(th, a0.z, accA);
            sp = fmaxf(th, 0.f) + __logf(1.f + __expf(-fabsf(th))); accS += sp;
            th = fi0 + fj.w + d0[3];
            accA = fmaf(th, a0.w, accA);
            sp = fmaxf(th, 0.f) + __logf(1.f + __expf(-fabsf(th))); accS += sp;

            th = fi1 + fj.x + d1[0];
            accA = fmaf(th, a1.x, accA);
            sp = fmaxf(th, 0.f) + __logf(1.f + __expf(-fabsf(th))); accS += sp;
            th = fi1 + fj.y + d1[1];
            accA = fmaf(th, a1.y, accA);
            sp = fmaxf(th, 0.f) + __logf(1.f + __expf(-fabsf(th))); accS += sp;
            th = fi1 + fj.z + d1[2];
            accA = fmaf(th, a1.z, accA);
            sp = fmaxf(th, 0.f) + __logf(1.f + __expf(-fabsf(th))); accS += sp;
            th = fi1 + fj.w + d1[3];
            accA = fmaf(th, a1.w, accA);
            sp = fmaxf(th, 0.f) + __logf(1.f + __expf(-fabsf(th))); accS += sp;
        }
    }

    accA = wave_reduce_sum(accA);
    accS = wave_reduce_sum(accS);
    __shared__ float rA[4], rS[4];
    if (lane == 0) { rA[tid >> 6] = accA; rS[tid >> 6] = accS; }
    __syncthreads();
    if (tid == 0) {
        part[blockIdx.x * 2]     = rA[0] + rA[1] + rA[2] + rA[3];
        part[blockIdx.x * 2 + 1] = rS[0] + rS[1] + rS[2] + rS[3];
    }
}

// ---------- K4: final deterministic reduction of 2048 block partials ----------
__global__ __launch_bounds__(1024) void kz_final(const float* __restrict__ part,
                                                 const double* __restrict__ acc,
                                                 float* __restrict__ out) {
    const int t = threadIdx.x;  // 1024 threads
    double dA = (double)part[2 * t]     + (double)part[2 * (t + 1024)];
    double dS = (double)part[2 * t + 1] + (double)part[2 * (t + 1024) + 1];
    #pragma unroll
    for (int off = 32; off > 0; off >>= 1) {
        dA += __shfl_down(dA, off);
        dS += __shfl_down(dS, off);
    }
    __shared__ double sA[16], sS[16];
    if ((t & 63) == 0) { sA[t >> 6] = dA; sS[t >> 6] = dS; }
    __syncthreads();
    if (t == 0) {
        double a = 0.0, s = 0.0;
        #pragma unroll
        for (int u = 0; u < 16; ++u) { a += sA[u]; s += sS[u]; }
        out[0] = (float)(0.5 * (a - (s - acc[2])));
    }
}

extern "C" void kernel_launch(void* const* d_in, const int* in_sizes, int n_in,
                              void* d_out, int out_size, void* d_ws, size_t ws_size,
                              hipStream_t stream) {
    const float* Ain    = (const float*)d_in[0];  // (N, N)
    const float* betain = (const float*)d_in[1];  // (N,)
    const float* ain    = (const float*)d_in[2];  // (1,)
    const float* Xin    = (const float*)d_in[3];  // (K, N)
    const float* Cin    = (const float*)d_in[4];  // (N, K)
    float* out = (float*)d_out;

    char* ws = (char*)d_ws;
    float*          Ep    = (float*)(ws + 0);                 // 4 KB (E' unnormalized)
    double*         acc   = (double*)(ws + 4096);             // 3 doubles (acc[2] = diag sp)
    float*          sC    = (float*)(ws + 4224);              // 128 B
    float*          f     = (float*)(ws + 8704);              // 32 KB
    float*          part  = (float*)(ws + 49152);             // 16 KB (2048 x float2)
    unsigned short* Xh    = (unsigned short*)(ws + 65536);    // 512 KB
    unsigned short* Wh    = (unsigned short*)(ws + 589824);   // 512 KB
    // total ~1.1 MB

    hipMemsetAsync(ws, 0, 4352, stream);  // zero Ep + accs + sC

    kE<<<256, 256, 0, stream>>>(Xin, Cin, Ep, sC);
    kp_prep<<<NN / 256, 256, 0, stream>>>(Xin, betain, ain, Ep, sC, f, Xh, Wh, acc);
    k_pair<<<2048, 256, 0, stream>>>(Ain, f, Xh, Wh, part);
    kz_final<<<1, 1024, 0, stream>>>(part, acc, out);
}